// Round 2
// baseline (200.202 us; speedup 1.0000x reference)
//
#include <hip/hip_runtime.h>

typedef short bf16x8 __attribute__((ext_vector_type(8)));
typedef float f32x4  __attribute__((ext_vector_type(4)));
typedef short sh4    __attribute__((ext_vector_type(4)));
typedef float fl4    __attribute__((ext_vector_type(4)));
typedef unsigned u32x2 __attribute__((ext_vector_type(2)));
typedef unsigned u32x4 __attribute__((ext_vector_type(4)));

#define B_N  4
#define C_N  256
#define NH_N 8
#define DK_N 32
#define N_N  1024
#define KN_N 3072

#if defined(__has_builtin)
#if __has_builtin(__builtin_amdgcn_permlane32_swap) && __has_builtin(__builtin_amdgcn_permlane16_swap)
#define USE_PERMLANE 1
#endif
#endif
#ifndef USE_PERMLANE
#define USE_PERMLANE 0
#endif

__device__ __forceinline__ short f2bf(float f) {   // RNE
    union { float f; unsigned u; } v; v.f = f;
    unsigned r = v.u + 0x7fffu + ((v.u >> 16) & 1u);
    return (short)(r >> 16);
}
__device__ __forceinline__ unsigned fbits(float f) {
    union { float f; unsigned u; } v; v.f = f; return v.u;
}

// ------------- kernel 1: prep streams + (z==12) weight fp32->bf16 -----------
// Xt[b*3+s][n][c] = bf16(gamma_s * x_s[b][c][n]);  Wbf = bf16(Wq|Wk|Wv|Wo)
__global__ __launch_bounds__(256) void prep_kernel(
    const float* __restrict__ x0, const float* __restrict__ x1,
    const float* __restrict__ x2, const float* __restrict__ g0,
    const float* __restrict__ g1, const float* __restrict__ g2,
    const float* __restrict__ Wq, const float* __restrict__ Wk,
    const float* __restrict__ Wv, const float* __restrict__ Wo,
    short* __restrict__ Xt, short* __restrict__ Wbf) {
    if (blockIdx.z == 12) {   // weight conversion: 64 blocks x 256 thr x 4x fl4
        int t = (blockIdx.y * 16 + blockIdx.x) * 256 + threadIdx.x;  // 0..16383
#pragma unroll
        for (int m = 0; m < 4; ++m) {
            const float* src = (m == 0) ? Wq : (m == 1) ? Wk : (m == 2) ? Wv : Wo;
            fl4 v = *reinterpret_cast<const fl4*>(src + t * 4);
            sh4 o;
            o.x = f2bf(v.x); o.y = f2bf(v.y); o.z = f2bf(v.z); o.w = f2bf(v.w);
            *reinterpret_cast<sh4*>(Wbf + m * 65536 + t * 4) = o;
        }
        return;
    }
    __shared__ float tile[64][65];
    int bs = blockIdx.z; int b = bs / 3; int s = bs - b * 3;
    int c0 = blockIdx.y * 64, n0 = blockIdx.x * 64;
    const float* xs = (s == 0) ? x0 : (s == 1) ? x1 : x2;
    float g = (s == 0) ? g0[0] : (s == 1) ? g1[0] : g2[0];
    int tx = threadIdx.x & 63, ty = threadIdx.x >> 6;
    const float* src = xs + (b * C_N + c0) * N_N + n0;
#pragma unroll
    for (int r = 0; r < 16; ++r) {
        int cl = ty * 16 + r;
        tile[cl][tx] = src[cl * N_N + tx] * g;
    }
    __syncthreads();
    short* dst = Xt + ((size_t)bs * N_N + n0) * C_N + c0;
#pragma unroll
    for (int r = 0; r < 16; ++r) {
        int nl = ty * 16 + r;
        dst[nl * C_N + tx] = f2bf(tile[tx][nl]);
    }
}

// ---------------- kernel 2: QKV GEMM  grid(112 ct, 4 mt, 4 b) ---------------
// ct 0-15: Q (stream 0); 16-63: K; 64-111: V (operand-swapped for C^T layout)
__global__ __launch_bounds__(256) void qkv_kernel(
    const short* __restrict__ Wbf, const float* __restrict__ bq,
    const float* __restrict__ bk, const float* __restrict__ bv,
    const short* __restrict__ Xt, short* __restrict__ Qs,
    short* __restrict__ Ks, short* __restrict__ Vt) {
    int b = blockIdx.z, mt = blockIdx.y, ct = blockIdx.x;
    int lane = threadIdx.x & 63, w = threadIdx.x >> 6;
    int l16 = lane & 15, quad = lane >> 4;
    int m0 = mt * 64;

    int type, s, n0;
    if (ct < 16)      { type = 0; s = 0;                 n0 = ct * 64; }
    else if (ct < 64) { type = 1; int c2 = ct - 16; s = c2 >> 4; n0 = (c2 & 15) * 64; }
    else              { type = 2; int c2 = ct - 64; s = c2 >> 4; n0 = (c2 & 15) * 64; }

    f32x4 acc[4];
#pragma unroll
    for (int i = 0; i < 4; ++i) acc[i] = f32x4{0.f, 0.f, 0.f, 0.f};

    if (type < 2) {
        const short* A    = Wbf + type * 65536;
        const float* bias = (type == 0) ? bq : bk;
        const short* Bsrc = Xt + ((size_t)(b * 3 + s) * N_N + n0) * C_N;
        int arow = m0 + w * 16 + l16;
#pragma unroll
        for (int kc = 0; kc < 256; kc += 32) {
            bf16x8 a = *reinterpret_cast<const bf16x8*>(A + arow * C_N + kc + quad * 8);
#pragma unroll
            for (int nt = 0; nt < 4; ++nt) {
                bf16x8 bb = *reinterpret_cast<const bf16x8*>(Bsrc + (nt * 16 + l16) * C_N + kc + quad * 8);
                acc[nt] = __builtin_amdgcn_mfma_f32_16x16x32_bf16(a, bb, acc[nt], 0, 0, 0);
            }
        }
        const float QSCALE = 0.17677669529663687f * 1.4426950408889634f;
        int row0 = m0 + w * 16 + quad * 4;          // 4 consecutive c_out rows
        int h = row0 >> 5, d0 = row0 & 31;          // h constant over r
        float b0_ = bias[row0], b1_ = bias[row0 + 1], b2_ = bias[row0 + 2], b3_ = bias[row0 + 3];
#pragma unroll
        for (int nt = 0; nt < 4; ++nt) {
            int col = n0 + nt * 16 + l16;
            float v0 = acc[nt][0] + b0_, v1 = acc[nt][1] + b1_;
            float v2 = acc[nt][2] + b2_, v3 = acc[nt][3] + b3_;
            sh4 pk;
            if (type == 0) {
                pk.x = f2bf(v0 * QSCALE); pk.y = f2bf(v1 * QSCALE);
                pk.z = f2bf(v2 * QSCALE); pk.w = f2bf(v3 * QSCALE);
                *reinterpret_cast<sh4*>(Qs + ((size_t)(b * NH_N + h) * N_N + col) * DK_N + d0) = pk;
            } else {
                pk.x = f2bf(v0); pk.y = f2bf(v1); pk.z = f2bf(v2); pk.w = f2bf(v3);
                *reinterpret_cast<sh4*>(Ks + ((size_t)(b * NH_N + h) * KN_N + s * N_N + col) * DK_N + d0) = pk;
            }
        }
    } else {
        // V: C^T orientation -> lane holds 4 consecutive positions for one c_out
        const short* Bw   = Wbf + 2 * 65536;
        const short* Asrc = Xt + (size_t)(b * 3 + s) * N_N * C_N;
        int apos = n0 + w * 16 + l16;
#pragma unroll
        for (int kc = 0; kc < 256; kc += 32) {
            bf16x8 ax = *reinterpret_cast<const bf16x8*>(Asrc + (size_t)apos * C_N + kc + quad * 8);
#pragma unroll
            for (int c2 = 0; c2 < 4; ++c2) {
                bf16x8 bw = *reinterpret_cast<const bf16x8*>(Bw + (size_t)(m0 + c2 * 16 + l16) * C_N + kc + quad * 8);
                acc[c2] = __builtin_amdgcn_mfma_f32_16x16x32_bf16(ax, bw, acc[c2], 0, 0, 0);
            }
        }
        int pos0 = n0 + w * 16 + quad * 4;
#pragma unroll
        for (int c2 = 0; c2 < 4; ++c2) {
            int co = m0 + c2 * 16 + l16;
            int h = co >> 5, d = co & 31;
            float bb_ = bv[co];
            sh4 pk;
            pk.x = f2bf(acc[c2][0] + bb_); pk.y = f2bf(acc[c2][1] + bb_);
            pk.z = f2bf(acc[c2][2] + bb_); pk.w = f2bf(acc[c2][3] + bb_);
            *reinterpret_cast<sh4*>(Vt + ((size_t)(b * NH_N + h) * DK_N + d) * KN_N + s * N_N + pos0) = pk;
        }
    }
}

// -------- kernel 3: fused attention, barrier-free, (almost) LDS-free --------
// S^T = mfma(K,Q); P transposed to A-layout in-register via permlane swaps.
#define EXPPACK(sv, Ra, Rb) {                                   \
    float p0 = __builtin_amdgcn_exp2f(sv[0]);                   \
    float p1 = __builtin_amdgcn_exp2f(sv[1]);                   \
    float p2 = __builtin_amdgcn_exp2f(sv[2]);                   \
    float p3 = __builtin_amdgcn_exp2f(sv[3]);                   \
    l_acc += (p0 + p1) + (p2 + p3);                             \
    Ra = __builtin_amdgcn_perm(fbits(p1), fbits(p0), 0x07060302u); \
    Rb = __builtin_amdgcn_perm(fbits(p3), fbits(p2), 0x07060302u); \
}

__global__ __launch_bounds__(256) void attn_kernel(
    const short* __restrict__ Qs, const short* __restrict__ Ks,
    const short* __restrict__ Vt, short* __restrict__ Ot) {
#if !USE_PERMLANE
    __shared__ short PT[4][16][76];
#endif
    int bh = blockIdx.x;
    int q0 = blockIdx.y * 64;
    int t = threadIdx.x, lane = t & 63, w = t >> 6;
    int l16 = lane & 15, quad = lane >> 4;

    bf16x8 q_frag = *reinterpret_cast<const bf16x8*>(
        Qs + ((size_t)bh * N_N + q0 + w * 16 + l16) * DK_N + quad * 8);
    const short* Kp  = Ks + ((size_t)bh * KN_N + l16) * DK_N + quad * 8;
    const short* Vp0 = Vt + ((size_t)bh * DK_N + l16) * KN_N + quad * 8;
    const short* Vp1 = Vp0 + 16 * KN_N;

    f32x4 o0 = {0.f, 0.f, 0.f, 0.f}, o1 = {0.f, 0.f, 0.f, 0.f};
    const f32x4 zero = {0.f, 0.f, 0.f, 0.f};
    float l_acc = 0.f;

    for (int kt = 0; kt < 48; ++kt) {
        int k0 = kt * 64;
        bf16x8 kf0 = *reinterpret_cast<const bf16x8*>(Kp + (k0 +  0) * DK_N);
        bf16x8 kf1 = *reinterpret_cast<const bf16x8*>(Kp + (k0 + 16) * DK_N);
        bf16x8 kf2 = *reinterpret_cast<const bf16x8*>(Kp + (k0 + 32) * DK_N);
        bf16x8 kf3 = *reinterpret_cast<const bf16x8*>(Kp + (k0 + 48) * DK_N);
        bf16x8 vf00 = *reinterpret_cast<const bf16x8*>(Vp0 + k0);
        bf16x8 vf01 = *reinterpret_cast<const bf16x8*>(Vp1 + k0);
        bf16x8 vf10 = *reinterpret_cast<const bf16x8*>(Vp0 + k0 + 32);
        bf16x8 vf11 = *reinterpret_cast<const bf16x8*>(Vp1 + k0 + 32);

        f32x4 s0 = __builtin_amdgcn_mfma_f32_16x16x32_bf16(kf0, q_frag, zero, 0, 0, 0);
        f32x4 s1 = __builtin_amdgcn_mfma_f32_16x16x32_bf16(kf1, q_frag, zero, 0, 0, 0);
        f32x4 s2 = __builtin_amdgcn_mfma_f32_16x16x32_bf16(kf2, q_frag, zero, 0, 0, 0);
        f32x4 s3 = __builtin_amdgcn_mfma_f32_16x16x32_bf16(kf3, q_frag, zero, 0, 0, 0);

        unsigned R00, R01, R10, R11, R20, R21, R30, R31;
        EXPPACK(s0, R00, R01);
        EXPPACK(s1, R10, R11);
        EXPPACK(s2, R20, R21);
        EXPPACK(s3, R30, R31);

#if USE_PERMLANE
        {   // ks = 0: keys k0..k0+31  (regs R0*, R1*)
            unsigned x0 = R00, y0 = R10, x1 = R01, y1 = R11;
            u32x2 r;
            r = __builtin_amdgcn_permlane32_swap(x0, y0, false, false); x0 = r.x; y0 = r.y;
            r = __builtin_amdgcn_permlane16_swap(x0, y0, false, false); x0 = r.x; y0 = r.y;
            r = __builtin_amdgcn_permlane32_swap(x1, y1, false, false); x1 = r.x; y1 = r.y;
            r = __builtin_amdgcn_permlane16_swap(x1, y1, false, false); x1 = r.x; y1 = r.y;
            union { u32x4 u; bf16x8 b; } pf; pf.u = u32x4{x0, x1, y0, y1};
            o0 = __builtin_amdgcn_mfma_f32_16x16x32_bf16(vf00, pf.b, o0, 0, 0, 0);
            o1 = __builtin_amdgcn_mfma_f32_16x16x32_bf16(vf01, pf.b, o1, 0, 0, 0);
        }
        {   // ks = 1: keys k0+32..k0+63  (regs R2*, R3*)
            unsigned x0 = R20, y0 = R30, x1 = R21, y1 = R31;
            u32x2 r;
            r = __builtin_amdgcn_permlane32_swap(x0, y0, false, false); x0 = r.x; y0 = r.y;
            r = __builtin_amdgcn_permlane16_swap(x0, y0, false, false); x0 = r.x; y0 = r.y;
            r = __builtin_amdgcn_permlane32_swap(x1, y1, false, false); x1 = r.x; y1 = r.y;
            r = __builtin_amdgcn_permlane16_swap(x1, y1, false, false); x1 = r.x; y1 = r.y;
            union { u32x4 u; bf16x8 b; } pf; pf.u = u32x4{x0, x1, y0, y1};
            o0 = __builtin_amdgcn_mfma_f32_16x16x32_bf16(vf10, pf.b, o0, 0, 0, 0);
            o1 = __builtin_amdgcn_mfma_f32_16x16x32_bf16(vf11, pf.b, o1, 0, 0, 0);
        }
#else
        {   // LDS fallback: per-wave private round-trip (no barriers needed)
            union { u32x2 u; sh4 s; } w0, w1, w2, w3;
            w0.u = u32x2{R00, R01}; w1.u = u32x2{R10, R11};
            w2.u = u32x2{R20, R21}; w3.u = u32x2{R30, R31};
            *reinterpret_cast<sh4*>(&PT[w][l16][ 0 + quad * 4]) = w0.s;
            *reinterpret_cast<sh4*>(&PT[w][l16][16 + quad * 4]) = w1.s;
            *reinterpret_cast<sh4*>(&PT[w][l16][32 + quad * 4]) = w2.s;
            *reinterpret_cast<sh4*>(&PT[w][l16][48 + quad * 4]) = w3.s;
            bf16x8 pf0 = *reinterpret_cast<bf16x8*>(&PT[w][l16][quad * 8]);
            bf16x8 pf1 = *reinterpret_cast<bf16x8*>(&PT[w][l16][32 + quad * 8]);
            o0 = __builtin_amdgcn_mfma_f32_16x16x32_bf16(vf00, pf0, o0, 0, 0, 0);
            o1 = __builtin_amdgcn_mfma_f32_16x16x32_bf16(vf01, pf0, o1, 0, 0, 0);
            o0 = __builtin_amdgcn_mfma_f32_16x16x32_bf16(vf10, pf1, o0, 0, 0, 0);
            o1 = __builtin_amdgcn_mfma_f32_16x16x32_bf16(vf11, pf1, o1, 0, 0, 0);
        }
#endif
    }

    // rowsum for q=l16 lives split across the 4 quads
    l_acc += __shfl_xor(l_acc, 16);
    l_acc += __shfl_xor(l_acc, 32);
    float rl = 1.0f / l_acc;

    int b = bh >> 3, h = bh & 7;
    int q = q0 + w * 16 + l16;
    short* Op = Ot + ((size_t)b * N_N + q) * C_N + h * DK_N + quad * 4;
    sh4 a0, a1;
    a0.x = f2bf(o0[0] * rl); a0.y = f2bf(o0[1] * rl);
    a0.z = f2bf(o0[2] * rl); a0.w = f2bf(o0[3] * rl);
    a1.x = f2bf(o1[0] * rl); a1.y = f2bf(o1[1] * rl);
    a1.z = f2bf(o1[2] * rl); a1.w = f2bf(o1[3] * rl);
    *reinterpret_cast<sh4*>(Op) = a0;
    *reinterpret_cast<sh4*>(Op + 16) = a1;
}

// ---------------- kernel 4: output projection  grid(16 ct, 4 mt, 4 b) -------
__global__ __launch_bounds__(256) void oproj_kernel(
    const short* __restrict__ Wo_bf, const float* __restrict__ bo,
    const short* __restrict__ Ot, float* __restrict__ out) {
    int b = blockIdx.z, mt = blockIdx.y, ct = blockIdx.x;
    int lane = threadIdx.x & 63, w = threadIdx.x >> 6;
    int l16 = lane & 15, quad = lane >> 4;
    int m0 = mt * 64, n0 = ct * 64;
    const short* Bsrc = Ot + ((size_t)b * N_N + n0) * C_N;
    int arow = m0 + w * 16 + l16;

    f32x4 acc[4];
#pragma unroll
    for (int i = 0; i < 4; ++i) acc[i] = f32x4{0.f, 0.f, 0.f, 0.f};

#pragma unroll
    for (int kc = 0; kc < 256; kc += 32) {
        bf16x8 a = *reinterpret_cast<const bf16x8*>(Wo_bf + arow * C_N + kc + quad * 8);
#pragma unroll
        for (int nt = 0; nt < 4; ++nt) {
            bf16x8 bb = *reinterpret_cast<const bf16x8*>(Bsrc + (nt * 16 + l16) * C_N + kc + quad * 8);
            acc[nt] = __builtin_amdgcn_mfma_f32_16x16x32_bf16(a, bb, acc[nt], 0, 0, 0);
        }
    }

#pragma unroll
    for (int r = 0; r < 4; ++r) {
        int row = m0 + w * 16 + quad * 4 + r;
        float bias = bo[row];
#pragma unroll
        for (int nt = 0; nt < 4; ++nt) {
            out[((size_t)b * C_N + row) * N_N + n0 + nt * 16 + l16] = acc[nt][r] + bias;
        }
    }
}

// ---------------------------------------------------------------------------
extern "C" void kernel_launch(void* const* d_in, const int* in_sizes, int n_in,
                              void* d_out, int out_size, void* d_ws, size_t ws_size,
                              hipStream_t stream) {
    const float* x0 = (const float*)d_in[0];
    const float* x1 = (const float*)d_in[1];
    const float* x2 = (const float*)d_in[2];
    const float* g0 = (const float*)d_in[3];
    const float* g1 = (const float*)d_in[4];
    const float* g2 = (const float*)d_in[5];
    const float* Wq = (const float*)d_in[6];
    const float* bq = (const float*)d_in[7];
    const float* Wk = (const float*)d_in[8];
    const float* bk = (const float*)d_in[9];
    const float* Wv = (const float*)d_in[10];
    const float* bv = (const float*)d_in[11];
    const float* Wo = (const float*)d_in[12];
    const float* bo = (const float*)d_in[13];
    float* out = (float*)d_out;

    char* wsb = (char*)d_ws;
    short* Wbf = (short*)(wsb + 0);            //  512 KB
    short* Xt  = (short*)(wsb + 524288);       // 6 MB: [12][1024][256]
    short* Qs  = (short*)(wsb + 6815744);      // 2 MB: [4][8][1024][32]
    short* Ks  = (short*)(wsb + 8912896);      // 6 MB: [4][8][3072][32]
    short* Vt  = (short*)(wsb + 15204352);     // 6 MB: [4][8][32][3072]
    short* Ot  = (short*)(wsb + 21495808);     // 2 MB: [4][1024][256]

    prep_kernel<<<dim3(16, 4, 13), 256, 0, stream>>>(x0, x1, x2, g0, g1, g2,
                                                     Wq, Wk, Wv, Wo, Xt, Wbf);
    qkv_kernel<<<dim3(112, 4, 4), 256, 0, stream>>>(Wbf, bq, bk, bv, Xt, Qs, Ks, Vt);
    attn_kernel<<<dim3(32, 16), 256, 0, stream>>>(Qs, Ks, Vt, Ot);
    oproj_kernel<<<dim3(16, 4, 4), 256, 0, stream>>>(Wbf + 3 * 65536, bo, Ot, out);
}